// Round 1
// baseline (4719.670 us; speedup 1.0000x reference)
//
#include <hip/hip_runtime.h>

#define NB 4
#define NPER 8192
#define MPER 2048
#define KNN 16
#define CIN 64
#define CO 128
#define MTOT (NB*MPER)

__device__ __forceinline__ float med3f(float a, float b, float c) {
    return __builtin_amdgcn_fmed3f(a, b, c);
}

// ---------------- init: zero stats + write row_splits ----------------
__global__ void k_init(float* __restrict__ stats, float* __restrict__ rs) {
    int t = threadIdx.x;
    if (t < 256) stats[t] = 0.f;
    if (t < 5) rs[t] = (float)(t * MPER);
}

// ---------------- FPS: one block per batch ----------------
__launch_bounds__(512, 1)
__global__ void k_fps(const float* __restrict__ pts, float* __restrict__ out_np,
                      float4* __restrict__ qpts) {
    #pragma clang fp contract(off)
    __shared__ float sx[NPER], sy[NPER], sz[NPER];
    __shared__ float red_v[8];
    __shared__ int   red_i[8];
    __shared__ float bc[3];
    const int b = blockIdx.x;
    const int t = threadIdx.x;
    const float4* pb4 = (const float4*)(pts + (size_t)b * NPER * 3);

    float px[16], py[16], pz[16], dd[16];
    float f[48];
    #pragma unroll
    for (int j = 0; j < 12; ++j) {
        float4 v = pb4[t * 12 + j];
        f[j*4+0] = v.x; f[j*4+1] = v.y; f[j*4+2] = v.z; f[j*4+3] = v.w;
    }
    #pragma unroll
    for (int s = 0; s < 16; ++s) {
        px[s] = f[s*3]; py[s] = f[s*3+1]; pz[s] = f[s*3+2];
        dd[s] = 1e10f;
        int gi = t * 16 + s;
        sx[gi] = px[s]; sy[gi] = py[s]; sz[gi] = pz[s];
    }
    if (t == 0) {
        bc[0] = px[0]; bc[1] = py[0]; bc[2] = pz[0];
        size_t row = (size_t)b * MPER;
        out_np[row*3+0] = px[0]; out_np[row*3+1] = py[0]; out_np[row*3+2] = pz[0];
        qpts[row] = make_float4(px[0], py[0], pz[0], 0.f);
    }
    __syncthreads();

    const int lane = t & 63, wv = t >> 6;
    const int ibase = t * 16;
    for (int i = 1; i < MPER; ++i) {
        float lx = bc[0], ly = bc[1], lz = bc[2];
        float bv = -1.f; int bi = 0x7fffffff;
        #pragma unroll
        for (int s = 0; s < 16; ++s) {
            float dx = px[s] - lx, dy = py[s] - ly, dz = pz[s] - lz;
            float t0 = dx * dx, t1 = dy * dy, t2 = dz * dz;
            float d = (t0 + t1) + t2;
            float nd = fminf(dd[s], d);
            dd[s] = nd;
            bool bet = nd > bv;
            bv = bet ? nd : bv;
            bi = bet ? (ibase + s) : bi;
        }
        #pragma unroll
        for (int off = 1; off < 64; off <<= 1) {
            float ov = __shfl_xor(bv, off);
            int   oi = __shfl_xor(bi, off);
            if (ov > bv || (ov == bv && oi < bi)) { bv = ov; bi = oi; }
        }
        if (lane == 0) { red_v[wv] = bv; red_i[wv] = bi; }
        __syncthreads();
        if (wv == 0) {
            float v2 = (lane < 8) ? red_v[lane] : -1.f;
            int   i2 = (lane < 8) ? red_i[lane] : 0x7fffffff;
            #pragma unroll
            for (int off = 1; off < 8; off <<= 1) {
                float ov = __shfl_xor(v2, off);
                int   oi = __shfl_xor(i2, off);
                if (ov > v2 || (ov == v2 && oi < i2)) { v2 = ov; i2 = oi; }
            }
            if (lane == 0) {
                float nx = sx[i2], ny = sy[i2], nz = sz[i2];
                bc[0] = nx; bc[1] = ny; bc[2] = nz;
                size_t row = (size_t)b * MPER + i;
                out_np[row*3+0] = nx; out_np[row*3+1] = ny; out_np[row*3+2] = nz;
                qpts[row] = make_float4(nx, ny, nz, 0.f);
            }
        }
        __syncthreads();
    }
}

// ---------------- KNN: 256 queries per block ----------------
#define CHUNK 2048
__launch_bounds__(256, 2)
__global__ void k_knn(const float* __restrict__ pts, const float4* __restrict__ qpts,
                      int* __restrict__ nidx) {
    #pragma clang fp contract(off)
    __shared__ float4 sp[CHUNK];
    __shared__ int cand[256][32];
    const int t = threadIdx.x;
    const int q = blockIdx.x * 256 + t;
    const int b = q >> 11;
    const float4 qp = qpts[q];
    const float qq = (qp.x * qp.x + qp.y * qp.y) + qp.z * qp.z;
    const float* pb = pts + (size_t)b * NPER * 3;

    float nd[16];
    #pragma unroll
    for (int j = 0; j < 16; ++j) nd[j] = 1e30f;

    // pass 1: top-16 distances only (med3 insert chain)
    for (int c = 0; c < NPER / CHUNK; ++c) {
        __syncthreads();
        #pragma unroll
        for (int r = 0; r < CHUNK / 256; ++r) {
            int li = r * 256 + t;
            int gi = c * CHUNK + li;
            float x = pb[gi*3], y = pb[gi*3+1], z = pb[gi*3+2];
            float pp = (x * x + y * y) + z * z;
            sp[li] = make_float4(x, y, z, pp);
        }
        __syncthreads();
        #pragma unroll 4
        for (int j = 0; j < CHUNK; ++j) {
            float4 p = sp[j];
            float dot = (qp.x * p.x + qp.y * p.y) + qp.z * p.z;
            float d = (qq + p.w) - 2.f * dot;
            if (d < nd[15]) {
                #pragma unroll
                for (int u = 15; u >= 1; --u) nd[u] = med3f(d, nd[u-1], nd[u]);
                nd[0] = fminf(nd[0], d);
            }
        }
    }
    const float tau = nd[15];

    // pass 2: collect indices with d <= tau (bit-identical recompute)
    int cnt = 0, cless = 0;
    for (int c = 0; c < NPER / CHUNK; ++c) {
        __syncthreads();
        #pragma unroll
        for (int r = 0; r < CHUNK / 256; ++r) {
            int li = r * 256 + t;
            int gi = c * CHUNK + li;
            float x = pb[gi*3], y = pb[gi*3+1], z = pb[gi*3+2];
            float pp = (x * x + y * y) + z * z;
            sp[li] = make_float4(x, y, z, pp);
        }
        __syncthreads();
        for (int j = 0; j < CHUNK; ++j) {
            float4 p = sp[j];
            float dot = (qp.x * p.x + qp.y * p.y) + qp.z * p.z;
            float d = (qq + p.w) - 2.f * dot;
            if (d <= tau && cnt < 32) {
                bool eq = !(d < tau);
                cand[t][cnt++] = (c * CHUNK + j) | (eq ? 0x80000000 : 0);
                if (!eq) cless++;
            }
        }
    }
    // quota selection: all (<tau) + first (16-cless) of (==tau), in scan order
    int quota = 16 - cless, kept = 0, eq_used = 0;
    for (int e = 0; e < cnt && kept < 16; ++e) {
        int v = cand[t][e];
        bool eq = (v & 0x80000000) != 0;
        int pidx = v & 0x7fffffff;
        bool take = !eq || (eq_used < quota);
        if (take) {
            if (eq) eq_used++;
            nidx[(size_t)q * KNN + kept] = b * NPER + pidx;
            kept++;
        }
    }
}

// ---------------- fused gather + linear + stats + k-minmax ----------------
// g layout per (m,k): [0..63]=feat, [64..66]=rel xyz, [67]=0 ; W reordered to match
__launch_bounds__(128, 4)
__global__ void k_stats(const float* __restrict__ pts, const float* __restrict__ feat,
                        const float* __restrict__ W, const int* __restrict__ nidx,
                        const float4* __restrict__ qpts, float* __restrict__ ymax,
                        float* __restrict__ ymin, float* __restrict__ stats) {
    __shared__ float4 g4[KNN][17];
    const int t = threadIdx.x; // channel o
    float w[68];
    const float* wr = W + t * 67;
    #pragma unroll
    for (int c = 0; c < 64; ++c) w[c] = wr[3 + c];
    w[64] = wr[0]; w[65] = wr[1]; w[66] = wr[2]; w[67] = 0.f;

    float s_sum = 0.f, s_sq = 0.f;
    const int k0 = t >> 3, p8 = t & 7;
    for (int mi = 0; mi < 8; ++mi) {
        const int m0 = blockIdx.x * 8 + mi;
        {
            int nid = nidx[(size_t)m0 * KNN + k0];
            const float4* fr = (const float4*)(feat + (size_t)nid * CIN);
            g4[k0][p8*2]   = fr[p8*2];
            g4[k0][p8*2+1] = fr[p8*2+1];
        }
        if (t < 16) {
            int nid = nidx[(size_t)m0 * KNN + t];
            float4 qp = qpts[m0];
            float x = pts[(size_t)nid*3], y = pts[(size_t)nid*3+1], z = pts[(size_t)nid*3+2];
            g4[t][16] = make_float4(x - qp.x, y - qp.y, z - qp.z, 0.f);
        }
        __syncthreads();
        float vmax = -1e30f, vmin = 1e30f;
        #pragma unroll 1
        for (int k = 0; k < KNN; ++k) {
            float y0 = 0.f, y1 = 0.f, y2 = 0.f, y3 = 0.f;
            #pragma unroll
            for (int c4 = 0; c4 < 17; ++c4) {
                float4 gv = g4[k][c4];
                y0 = fmaf(gv.x, w[c4*4+0], y0);
                y1 = fmaf(gv.y, w[c4*4+1], y1);
                y2 = fmaf(gv.z, w[c4*4+2], y2);
                y3 = fmaf(gv.w, w[c4*4+3], y3);
            }
            float y = (y0 + y1) + (y2 + y3);
            vmax = fmaxf(vmax, y); vmin = fminf(vmin, y);
            s_sum += y; s_sq = fmaf(y, y, s_sq);
        }
        ymax[(size_t)m0 * CO + t] = vmax;
        ymin[(size_t)m0 * CO + t] = vmin;
        __syncthreads();
    }
    atomicAdd(stats + t, s_sum);
    atomicAdd(stats + CO + t, s_sq);
}

// ---------------- finalize BN scale/shift ----------------
__global__ void k_final(const float* __restrict__ stats, const float* __restrict__ gamma,
                        const float* __restrict__ beta, float* __restrict__ sb) {
    int o = threadIdx.x;
    const float inv = 1.f / (float)(MTOT * KNN);
    float mean = stats[o] * inv;
    float var = stats[CO + o] * inv - mean * mean;
    var = fmaxf(var, 0.f);
    float s = gamma[o] * rsqrtf(var + 1e-5f);
    sb[o] = s;
    sb[CO + o] = beta[o] - mean * s;
}

// ---------------- epilogue: relu(s*ext + b) ----------------
__global__ void k_out(const float* __restrict__ ymax, const float* __restrict__ ymin,
                      const float* __restrict__ sb, float* __restrict__ out_feat) {
    int tid = blockIdx.x * 256 + threadIdx.x;
    int o = tid & (CO - 1);
    float s = sb[o], bb = sb[CO + o];
    float yv = (s >= 0.f) ? ymax[tid] : ymin[tid];
    out_feat[tid] = fmaxf(fmaf(s, yv, bb), 0.f);
}

extern "C" void kernel_launch(void* const* d_in, const int* in_sizes, int n_in,
                              void* d_out, int out_size, void* d_ws, size_t ws_size,
                              hipStream_t stream) {
    const float* pts   = (const float*)d_in[0];
    const float* feat  = (const float*)d_in[1];
    const float* W     = (const float*)d_in[3];
    const float* gamma = (const float*)d_in[4];
    const float* beta  = (const float*)d_in[5];
    float* out = (float*)d_out;
    char* ws = (char*)d_ws;

    float4* qpts = (float4*)(ws);                       // 131072 B
    int*    nidx = (int*)(ws + 131072);                 // 524288 B
    float*  stats = (float*)(ws + 655360);              // 1024 B
    float*  sb    = (float*)(ws + 656384);              // 1024 B
    float*  ymax  = (float*)(ws + 657408);              // 4 MB
    float*  ymin  = (float*)(ws + 657408 + 4194304);    // 4 MB

    float* out_np   = out;                    // (8192,3)
    float* out_feat = out + 24576;            // (8192,128)
    float* out_rs   = out + 24576 + 1048576;  // (5,)

    hipLaunchKernelGGL(k_init,  dim3(1), dim3(256), 0, stream, stats, out_rs);
    hipLaunchKernelGGL(k_fps,   dim3(NB), dim3(512), 0, stream, pts, out_np, qpts);
    hipLaunchKernelGGL(k_knn,   dim3(MTOT / 256), dim3(256), 0, stream, pts, qpts, nidx);
    hipLaunchKernelGGL(k_stats, dim3(MTOT / 8), dim3(128), 0, stream,
                       pts, feat, W, nidx, qpts, ymax, ymin, stats);
    hipLaunchKernelGGL(k_final, dim3(1), dim3(128), 0, stream, stats, gamma, beta, sb);
    hipLaunchKernelGGL(k_out,   dim3(MTOT * CO / 256), dim3(256), 0, stream,
                       ymax, ymin, sb, out_feat);
}

// Round 2
// 3362.452 us; speedup vs baseline: 1.4036x; 1.4036x over previous
//
#include <hip/hip_runtime.h>

#define NB 4
#define NPER 8192
#define MPER 2048
#define KNN 16
#define CIN 64
#define CO 128
#define MTOT (NB*MPER)

__device__ __forceinline__ float med3f(float a, float b, float c) {
    return __builtin_amdgcn_fmed3f(a, b, c);
}

// ---------------- init: zero stats + write row_splits ----------------
__global__ void k_init(float* __restrict__ stats, float* __restrict__ rs) {
    int t = threadIdx.x;
    if (t < 256) stats[t] = 0.f;
    if (t < 5) rs[t] = (float)(t * MPER);
}

// DPP compare-select step on a packed u64 key (max). Masked-out lanes keep old.
#define DPPSTEP(key, CTRL, RM) do {                                                   \
    unsigned lo_ = (unsigned)(key), hi_ = (unsigned)((key) >> 32);                    \
    unsigned nlo = (unsigned)__builtin_amdgcn_update_dpp((int)lo_, (int)lo_, CTRL, RM, 0xf, false); \
    unsigned nhi = (unsigned)__builtin_amdgcn_update_dpp((int)hi_, (int)hi_, CTRL, RM, 0xf, false); \
    unsigned long long ok_ = ((unsigned long long)nhi << 32) | nlo;                   \
    if (ok_ > (key)) (key) = ok_;                                                     \
} while (0)

// ---------------- FPS: one block per batch, 256 threads, 32 pts/lane ----------------
__launch_bounds__(256, 1)
__global__ void k_fps(const float* __restrict__ pts, float* __restrict__ out_np,
                      float4* __restrict__ qpts) {
    #pragma clang fp contract(off)
    __shared__ float4 spt[NPER];                 // 128 KiB point table (x,y,z,0)
    __shared__ unsigned long long red[2][4];     // parity-double-buffered wave partials
    const int b = blockIdx.x;
    const int t = threadIdx.x;
    const float4* pb4 = (const float4*)(pts + (size_t)b * NPER * 3);

    // load my 32 points (96 floats = 24 float4) straight into registers
    float f[96];
    #pragma unroll
    for (int j = 0; j < 24; ++j) {
        float4 v = pb4[t * 24 + j];
        f[j*4+0] = v.x; f[j*4+1] = v.y; f[j*4+2] = v.z; f[j*4+3] = v.w;
    }
    float px[32], py[32], pz[32], dd[32];
    #pragma unroll
    for (int s = 0; s < 32; ++s) {
        px[s] = f[3*s]; py[s] = f[3*s+1]; pz[s] = f[3*s+2];
        dd[s] = 1e10f;
        spt[t * 32 + s] = make_float4(px[s], py[s], pz[s], 0.f);
    }
    if (t == 0) {
        size_t row = (size_t)b * MPER;
        out_np[row*3+0] = px[0]; out_np[row*3+1] = py[0]; out_np[row*3+2] = pz[0];
        qpts[row] = make_float4(px[0], py[0], pz[0], 0.f);
    }
    __syncthreads();

    float4 c0 = spt[0];
    float cx = c0.x, cy = c0.y, cz = c0.z;

    for (int i = 1; i < MPER; ++i) {
        // local argmax over my 32 slots (exact ref arithmetic, strict > keeps lowest idx)
        float bv = -1.f; int bs = 0;
        #pragma unroll
        for (int s = 0; s < 32; ++s) {
            float dx = px[s] - cx, dy = py[s] - cy, dz = pz[s] - cz;
            float t0 = dx * dx, t1 = dy * dy, t2 = dz * dz;
            float d = (t0 + t1) + t2;
            float nd = fminf(dd[s], d);
            dd[s] = nd;
            bool bet = nd > bv;
            bv = bet ? nd : bv;
            bs = bet ? s : bs;
        }
        unsigned long long key =
            ((unsigned long long)__float_as_uint(bv) << 32) | (unsigned)~(t * 32 + bs);

        // 64-lane max via DPP (VALU latency, no LDS round-trips)
        DPPSTEP(key, 0xB1,  0xF);   // quad_perm xor1
        DPPSTEP(key, 0x4E,  0xF);   // quad_perm xor2
        DPPSTEP(key, 0x141, 0xF);   // row_half_mirror (8)
        DPPSTEP(key, 0x140, 0xF);   // row_mirror (16)
        DPPSTEP(key, 0x142, 0xA);   // row_bcast15 -> rows 1,3
        DPPSTEP(key, 0x143, 0xC);   // row_bcast31 -> rows 2,3  (lane63 = full max)

        if ((t & 63) == 63) red[i & 1][t >> 6] = key;
        __syncthreads();            // single barrier; parity buffer avoids WAW

        const int p = i & 1;
        unsigned long long k0 = red[p][0], k1 = red[p][1], k2 = red[p][2], k3 = red[p][3];
        unsigned long long ka = k0 > k1 ? k0 : k1;
        unsigned long long kb = k2 > k3 ? k2 : k3;
        unsigned long long kbest = ka > kb ? ka : kb;
        const int i2 = (int)(~(unsigned)kbest);

        float4 c = spt[i2];         // broadcast read, every thread fetches centroid itself
        cx = c.x; cy = c.y; cz = c.z;

        if (t == 0) {
            size_t row = (size_t)b * MPER + i;
            out_np[row*3+0] = cx; out_np[row*3+1] = cy; out_np[row*3+2] = cz;
            qpts[row] = make_float4(cx, cy, cz, 0.f);
        }
    }
}

// ---------------- KNN: 256 queries per block ----------------
#define CHUNK 2048
__launch_bounds__(256, 2)
__global__ void k_knn(const float* __restrict__ pts, const float4* __restrict__ qpts,
                      int* __restrict__ nidx) {
    #pragma clang fp contract(off)
    __shared__ float4 sp[CHUNK];
    __shared__ int cand[256][32];
    const int t = threadIdx.x;
    const int q = blockIdx.x * 256 + t;
    const int b = q >> 11;
    const float4 qp = qpts[q];
    const float qq = (qp.x * qp.x + qp.y * qp.y) + qp.z * qp.z;
    const float* pb = pts + (size_t)b * NPER * 3;

    float nd[16];
    #pragma unroll
    for (int j = 0; j < 16; ++j) nd[j] = 1e30f;

    // pass 1: top-16 distances only (med3 insert chain)
    for (int c = 0; c < NPER / CHUNK; ++c) {
        __syncthreads();
        #pragma unroll
        for (int r = 0; r < CHUNK / 256; ++r) {
            int li = r * 256 + t;
            int gi = c * CHUNK + li;
            float x = pb[gi*3], y = pb[gi*3+1], z = pb[gi*3+2];
            float pp = (x * x + y * y) + z * z;
            sp[li] = make_float4(x, y, z, pp);
        }
        __syncthreads();
        #pragma unroll 4
        for (int j = 0; j < CHUNK; ++j) {
            float4 p = sp[j];
            float dot = (qp.x * p.x + qp.y * p.y) + qp.z * p.z;
            float d = (qq + p.w) - 2.f * dot;
            if (d < nd[15]) {
                #pragma unroll
                for (int u = 15; u >= 1; --u) nd[u] = med3f(d, nd[u-1], nd[u]);
                nd[0] = fminf(nd[0], d);
            }
        }
    }
    const float tau = nd[15];

    // pass 2: collect indices with d <= tau (bit-identical recompute)
    int cnt = 0, cless = 0;
    for (int c = 0; c < NPER / CHUNK; ++c) {
        __syncthreads();
        #pragma unroll
        for (int r = 0; r < CHUNK / 256; ++r) {
            int li = r * 256 + t;
            int gi = c * CHUNK + li;
            float x = pb[gi*3], y = pb[gi*3+1], z = pb[gi*3+2];
            float pp = (x * x + y * y) + z * z;
            sp[li] = make_float4(x, y, z, pp);
        }
        __syncthreads();
        for (int j = 0; j < CHUNK; ++j) {
            float4 p = sp[j];
            float dot = (qp.x * p.x + qp.y * p.y) + qp.z * p.z;
            float d = (qq + p.w) - 2.f * dot;
            if (d <= tau && cnt < 32) {
                bool eq = !(d < tau);
                cand[t][cnt++] = (c * CHUNK + j) | (eq ? 0x80000000 : 0);
                if (!eq) cless++;
            }
        }
    }
    // quota selection: all (<tau) + first (16-cless) of (==tau), in scan order
    int quota = 16 - cless, kept = 0, eq_used = 0;
    for (int e = 0; e < cnt && kept < 16; ++e) {
        int v = cand[t][e];
        bool eq = (v & 0x80000000) != 0;
        int pidx = v & 0x7fffffff;
        bool take = !eq || (eq_used < quota);
        if (take) {
            if (eq) eq_used++;
            nidx[(size_t)q * KNN + kept] = b * NPER + pidx;
            kept++;
        }
    }
}

// ---------------- fused gather + linear + stats + k-minmax ----------------
__launch_bounds__(128, 4)
__global__ void k_stats(const float* __restrict__ pts, const float* __restrict__ feat,
                        const float* __restrict__ W, const int* __restrict__ nidx,
                        const float4* __restrict__ qpts, float* __restrict__ ymax,
                        float* __restrict__ ymin, float* __restrict__ stats) {
    __shared__ float4 g4[KNN][17];
    const int t = threadIdx.x; // channel o
    float w[68];
    const float* wr = W + t * 67;
    #pragma unroll
    for (int c = 0; c < 64; ++c) w[c] = wr[3 + c];
    w[64] = wr[0]; w[65] = wr[1]; w[66] = wr[2]; w[67] = 0.f;

    float s_sum = 0.f, s_sq = 0.f;
    const int k0 = t >> 3, p8 = t & 7;
    for (int mi = 0; mi < 8; ++mi) {
        const int m0 = blockIdx.x * 8 + mi;
        {
            int nid = nidx[(size_t)m0 * KNN + k0];
            const float4* fr = (const float4*)(feat + (size_t)nid * CIN);
            g4[k0][p8*2]   = fr[p8*2];
            g4[k0][p8*2+1] = fr[p8*2+1];
        }
        if (t < 16) {
            int nid = nidx[(size_t)m0 * KNN + t];
            float4 qp = qpts[m0];
            float x = pts[(size_t)nid*3], y = pts[(size_t)nid*3+1], z = pts[(size_t)nid*3+2];
            g4[t][16] = make_float4(x - qp.x, y - qp.y, z - qp.z, 0.f);
        }
        __syncthreads();
        float vmax = -1e30f, vmin = 1e30f;
        #pragma unroll 1
        for (int k = 0; k < KNN; ++k) {
            float y0 = 0.f, y1 = 0.f, y2 = 0.f, y3 = 0.f;
            #pragma unroll
            for (int c4 = 0; c4 < 17; ++c4) {
                float4 gv = g4[k][c4];
                y0 = fmaf(gv.x, w[c4*4+0], y0);
                y1 = fmaf(gv.y, w[c4*4+1], y1);
                y2 = fmaf(gv.z, w[c4*4+2], y2);
                y3 = fmaf(gv.w, w[c4*4+3], y3);
            }
            float y = (y0 + y1) + (y2 + y3);
            vmax = fmaxf(vmax, y); vmin = fminf(vmin, y);
            s_sum += y; s_sq = fmaf(y, y, s_sq);
        }
        ymax[(size_t)m0 * CO + t] = vmax;
        ymin[(size_t)m0 * CO + t] = vmin;
        __syncthreads();
    }
    atomicAdd(stats + t, s_sum);
    atomicAdd(stats + CO + t, s_sq);
}

// ---------------- finalize BN scale/shift ----------------
__global__ void k_final(const float* __restrict__ stats, const float* __restrict__ gamma,
                        const float* __restrict__ beta, float* __restrict__ sb) {
    int o = threadIdx.x;
    const float inv = 1.f / (float)(MTOT * KNN);
    float mean = stats[o] * inv;
    float var = stats[CO + o] * inv - mean * mean;
    var = fmaxf(var, 0.f);
    float s = gamma[o] * rsqrtf(var + 1e-5f);
    sb[o] = s;
    sb[CO + o] = beta[o] - mean * s;
}

// ---------------- epilogue: relu(s*ext + b) ----------------
__global__ void k_out(const float* __restrict__ ymax, const float* __restrict__ ymin,
                      const float* __restrict__ sb, float* __restrict__ out_feat) {
    int tid = blockIdx.x * 256 + threadIdx.x;
    int o = tid & (CO - 1);
    float s = sb[o], bb = sb[CO + o];
    float yv = (s >= 0.f) ? ymax[tid] : ymin[tid];
    out_feat[tid] = fmaxf(fmaf(s, yv, bb), 0.f);
}

extern "C" void kernel_launch(void* const* d_in, const int* in_sizes, int n_in,
                              void* d_out, int out_size, void* d_ws, size_t ws_size,
                              hipStream_t stream) {
    const float* pts   = (const float*)d_in[0];
    const float* feat  = (const float*)d_in[1];
    const float* W     = (const float*)d_in[3];
    const float* gamma = (const float*)d_in[4];
    const float* beta  = (const float*)d_in[5];
    float* out = (float*)d_out;
    char* ws = (char*)d_ws;

    float4* qpts = (float4*)(ws);                       // 131072 B
    int*    nidx = (int*)(ws + 131072);                 // 524288 B
    float*  stats = (float*)(ws + 655360);              // 1024 B
    float*  sb    = (float*)(ws + 656384);              // 1024 B
    float*  ymax  = (float*)(ws + 657408);              // 4 MB
    float*  ymin  = (float*)(ws + 657408 + 4194304);    // 4 MB

    float* out_np   = out;                    // (8192,3)
    float* out_feat = out + 24576;            // (8192,128)
    float* out_rs   = out + 24576 + 1048576;  // (5,)

    hipLaunchKernelGGL(k_init,  dim3(1), dim3(256), 0, stream, stats, out_rs);
    hipLaunchKernelGGL(k_fps,   dim3(NB), dim3(256), 0, stream, pts, out_np, qpts);
    hipLaunchKernelGGL(k_knn,   dim3(MTOT / 256), dim3(256), 0, stream, pts, qpts, nidx);
    hipLaunchKernelGGL(k_stats, dim3(MTOT / 8), dim3(128), 0, stream,
                       pts, feat, W, nidx, qpts, ymax, ymin, stats);
    hipLaunchKernelGGL(k_final, dim3(1), dim3(128), 0, stream, stats, gamma, beta, sb);
    hipLaunchKernelGGL(k_out,   dim3(MTOT * CO / 256), dim3(256), 0, stream,
                       ymax, ymin, sb, out_feat);
}